// Round 6
// baseline (191.587 us; speedup 1.0000x reference)
//
#include <hip/hip_runtime.h>
#include <hip/hip_bf16.h>
#include <math.h>

#define B_N 512
#define C_N 100000
#define CPAD 100032          // padded to multiple of 64
#define D_N 128
#define NCHUNK (CPAD / 64)   // 1563
#define K5_BLOCKS (CPAD / 4) // 25008
#define K6_GX 256
#define K6_GY 4
#define K6_BLOCKS (K6_GX * K6_GY)
// each proxy pad row (zero vector) contributes exp(-18) to every row's sumexp
#define PAD_CORR (32.0f * 1.522998e-8f)

typedef short short8 __attribute__((ext_vector_type(8)));
typedef float f32x4 __attribute__((ext_vector_type(4)));

__device__ __forceinline__ unsigned short f2bf(float f) {
  unsigned int u = __float_as_uint(f);
  u += 0x7fffu + ((u >> 16) & 1u);
  return (unsigned short)(u >> 16);
}

template <int NT>
__device__ __forceinline__ float block_reduce_sum(float v, float* red) {
  int t = threadIdx.x;
  __syncthreads();
  red[t] = v;
  __syncthreads();
#pragma unroll
  for (int s = NT / 2; s > 0; s >>= 1) {
    if (t < s) red[t] += red[t + s];
    __syncthreads();
  }
  return red[0];
}

// kA: fused proxy-normalize (blocks [0,K5_BLOCKS)) + X-normalize/Pb/diag + X2 zero
__global__ __launch_bounds__(256) void kA(const float* __restrict__ X,
                                          const float* __restrict__ proxies,
                                          const int* __restrict__ T,
                                          float* __restrict__ Xn, float* __restrict__ Pb,
                                          float* __restrict__ diagv, float* __restrict__ X2,
                                          unsigned short* __restrict__ Pnb) {
  int bid = blockIdx.x;
  int t = threadIdx.x;
  if (bid < K5_BLOCKS) {
    int lane = t & 63;
    int row = bid * 4 + (t >> 6);
    float2 v = make_float2(0.f, 0.f);
    if (row < C_N) v = *(const float2*)(proxies + (size_t)row * D_N + 2 * lane);
    float ss = v.x * v.x + v.y * v.y;
#pragma unroll
    for (int off = 1; off < 64; off <<= 1) ss += __shfl_xor(ss, off);
    float inv = 1.f / fmaxf(sqrtf(ss), 1e-12f);
    unsigned short a = f2bf(v.x * inv), b = f2bf(v.y * inv);
    unsigned int pk = (unsigned int)a | ((unsigned int)b << 16);
    *(unsigned int*)(Pnb + (size_t)row * D_N + 2 * lane) = pk;  // pad rows -> exact zeros
  } else {
    __shared__ float red[256];
    int b = bid - K5_BLOCKS;
    bool act = t < D_N;
    float v = act ? X[b * D_N + t] : 0.f;
    float ss = block_reduce_sum<256>(v * v, red);
    float xn = v / fmaxf(sqrtf(ss), 1e-12f);
    if (act) {
      Xn[b * D_N + t] = xn;
      X2[b * D_N + t] = 0.f;
    }
    int row = T[b];
    float p = act ? proxies[(size_t)row * D_N + t] : 0.f;
    float ss2 = block_reduce_sum<256>(p * p, red);
    float pn = p / fmaxf(sqrtf(ss2), 1e-12f);
    if (act) Pb[b * D_N + t] = pn;
    float d = block_reduce_sum<256>(pn * xn, red);
    if (t == 0) diagv[b] = d;
  }
}

// K3: A[b,k] = relu(0.5*(Pb[b].Xn[k]+diag[k])) + relu(Xn[b].Xn[k]); S[b]=row sum
__global__ __launch_bounds__(256) void k3_att(const float* __restrict__ Xn,
                                              const float* __restrict__ Pb,
                                              const float* __restrict__ diagv,
                                              float* __restrict__ A, float* __restrict__ S) {
  __shared__ float xb[128], pbv[128];
  __shared__ float red[256];
  int b = blockIdx.x, t = threadIdx.x;
  if (t < 128) {
    xb[t] = Xn[b * D_N + t];
    pbv[t] = Pb[b * D_N + t];
  }
  __syncthreads();
  float rs = 0.f;
  for (int k = t; k < B_N; k += 256) {
    const float4* xr = (const float4*)(Xn + (size_t)k * D_N);
    float d1 = 0.f, d2 = 0.f;
#pragma unroll
    for (int i = 0; i < 32; i++) {
      float4 v = xr[i];
      d1 += pbv[4 * i] * v.x + pbv[4 * i + 1] * v.y + pbv[4 * i + 2] * v.z + pbv[4 * i + 3] * v.w;
      d2 += xb[4 * i] * v.x + xb[4 * i + 1] * v.y + xb[4 * i + 2] * v.z + xb[4 * i + 3] * v.w;
    }
    float a = fmaxf(0.5f * (d1 + diagv[k]), 0.f) + fmaxf(d2, 0.f);
    A[(size_t)b * B_N + k] = a;
    rs += a;
  }
  rs = block_reduce_sum<256>(rs, red);
  if (t == 0) S[b] = rs;
}

// K4a: X2[b,:] += sum over k-slice of (A[b,k]/(S[k]+eps)) * Xn[k,:]   grid (512,4)
__global__ void k4a_aw(const float* __restrict__ Xn, const float* __restrict__ A,
                       const float* __restrict__ S, float* __restrict__ X2) {
  __shared__ float aw[128];
  int b = blockIdx.x, t = threadIdx.x;
  int k0 = blockIdx.y * 128;
  aw[t] = A[(size_t)b * B_N + k0 + t] / (S[k0 + t] + 1e-5f);
  __syncthreads();
  float acc = 0.f;
#pragma unroll 16
  for (int kk = 0; kk < 128; kk++) acc += aw[kk] * Xn[(size_t)(k0 + kk) * D_N + t];
  atomicAdd(&X2[b * D_N + t], acc);
}

// K4b: Xsb = bf16(3*l2norm(Xn+X2)); lossT[b] = max(18-6*Xs.Pb,0); zero k6 state
__global__ void k4b_xs(const float* __restrict__ Xn, const float* __restrict__ X2,
                       const float* __restrict__ Pb, unsigned short* __restrict__ Xsb,
                       float* __restrict__ lossT, float* __restrict__ sumexpP,
                       int* __restrict__ ctrs) {
  __shared__ float red[128];
  int b = blockIdx.x, t = threadIdx.x;
  float x2 = Xn[b * D_N + t] + X2[b * D_N + t];
  float ss = block_reduce_sum<128>(x2 * x2, red);
  float xs = 3.f * x2 / fmaxf(sqrtf(ss), 1e-12f);
  Xsb[b * D_N + t] = f2bf(xs);
  float dt = block_reduce_sum<128>(xs * Pb[b * D_N + t], red);
  if (t == 0) {
    lossT[b] = fmaxf(18.f - 6.f * dt, 0.f);
    sumexpP[b * 16] = 0.f;
    if (b == 0) ctrs[32] = 0;  // arrive counter, own cache line
  }
}

// K6: Dm[b,c] = max(18 - 6*dot(Xs[b], Pn[c]), 0); sumexp[b] += sum_c exp(-Dm)
// grid (256,4), block 256 = 4 independent waves. NO LDS, NO barriers in the
// hot loop: B-fragments are contiguous 16 B rows-slices of Pnb, loaded
// straight global->VGPR (the LDS-DMA + syncthreads vmcnt(0) drain was the
// ~15K cyc/iter stall). Waves drift independently; compiler emits
// fine-grained vmcnt for VGPR loads.
__global__ __launch_bounds__(256, 3) void k6_big(const unsigned short* __restrict__ Pnb,
                                                 const unsigned short* __restrict__ Xsb,
                                                 float* __restrict__ sumexpP,
                                                 const float* __restrict__ lossT,
                                                 int* __restrict__ ctrs,
                                                 float* __restrict__ out) {
  __shared__ float redf[256];
  __shared__ int sLast;
  const int t = threadIdx.x;
  const int w = t >> 6;
  const int lane = t & 63;
  const int lc = lane & 15;
  const int q = lane >> 4;
  const int b0 = blockIdx.y * 128;

  // A-fragments once from global bf16 Xsb: A[m=lc][k=ks*32+q*8+j]
  short8 afr[2][4];
#pragma unroll
  for (int mt = 0; mt < 2; mt++)
#pragma unroll
    for (int ks = 0; ks < 4; ks++)
      afr[mt][ks] = *(const short8*)(Xsb + (size_t)(b0 + 32 * w + 16 * mt + lc) * D_N +
                                     ks * 32 + q * 8);

  float pe[2][4];
#pragma unroll
  for (int mt = 0; mt < 2; mt++)
#pragma unroll
    for (int r = 0; r < 4; r++) pe[mt][r] = 0.f;

  // per-lane B-frag offset within a 64-row chunk: row 16*nt+lc, bytes ks*64+q*16
  const int boff = lc * D_N + q * 8;  // element offset; +nt*16*D_N +ks*32 per frag

  for (int cc = blockIdx.x; cc < NCHUNK; cc += K6_GX) {
    const unsigned short* bp = Pnb + ((size_t)cc << 13);  // cc*64*128

    short8 bfr[4][4];  // [ks][nt]
#pragma unroll
    for (int ks = 0; ks < 4; ks++)
#pragma unroll
      for (int nt = 0; nt < 4; nt++)
        bfr[ks][nt] = *(const short8*)(bp + boff + nt * (16 * D_N) + ks * 32);

    f32x4 acc[2][4];
#pragma unroll
    for (int mt = 0; mt < 2; mt++)
#pragma unroll
      for (int nt = 0; nt < 4; nt++) acc[mt][nt] = (f32x4){0.f, 0.f, 0.f, 0.f};

#pragma unroll
    for (int ks = 0; ks < 4; ks++)
#pragma unroll
      for (int nt = 0; nt < 4; nt++) {
        acc[0][nt] = __builtin_amdgcn_mfma_f32_16x16x32_bf16(afr[0][ks], bfr[ks][nt],
                                                             acc[0][nt], 0, 0, 0);
        acc[1][nt] = __builtin_amdgcn_mfma_f32_16x16x32_bf16(afr[1][ks], bfr[ks][nt],
                                                             acc[1][nt], 0, 0, 0);
      }

    // epilogue: no bounds predicate — pad rows are zero vectors, corrected at end
#pragma unroll
    for (int mt = 0; mt < 2; mt++)
#pragma unroll
      for (int nt = 0; nt < 4; nt++) {
        f32x4 a = acc[mt][nt];
#pragma unroll
        for (int r = 0; r < 4; r++)
          pe[mt][r] += __expf(fminf(6.f * a[r] - 18.f, 0.f));
      }
  }

  // reduce over 16 col-lanes; one padded atomic per row
#pragma unroll
  for (int mt = 0; mt < 2; mt++) {
#pragma unroll
    for (int r = 0; r < 4; r++) {
      float p = pe[mt][r];
      p += __shfl_xor(p, 1);
      p += __shfl_xor(p, 2);
      p += __shfl_xor(p, 4);
      p += __shfl_xor(p, 8);
      if (lc == 0) {
        int rb = b0 + 32 * w + 16 * mt + 4 * q + r;
        atomicAdd(&sumexpP[rb * 16], p);
      }
    }
  }

  // fused k7: last block to arrive reduces the loss. Atomics complete at the
  // device coherence point; ordering needs only vmcnt(0) (NO threadfence --
  // agent fences emit L2 writeback/invalidate, measured ~46 us over the grid).
  __builtin_amdgcn_s_waitcnt(0);
  if (t == 0) sLast = atomicAdd(&ctrs[32], 1);
  __syncthreads();
  if (sLast == K6_BLOCKS - 1) {
    float v = 0.f;
#pragma unroll
    for (int i = 0; i < 2; i++) {
      int b = t + 256 * i;
      float se = __hip_atomic_load(&sumexpP[b * 16], __ATOMIC_RELAXED,
                                   __HIP_MEMORY_SCOPE_AGENT);
      v += lossT[b] + logf(se - PAD_CORR);
    }
    float s = block_reduce_sum<256>(v, redf);
    if (t == 0) out[0] = s * (1.0f / 512.0f);
  }
}

extern "C" void kernel_launch(void* const* d_in, const int* in_sizes, int n_in,
                              void* d_out, int out_size, void* d_ws, size_t ws_size,
                              hipStream_t stream) {
  const float* X = (const float*)d_in[0];
  const int* T = (const int*)d_in[2];
  const float* proxies = (const float*)d_in[3];
  float* out = (float*)d_out;

  char* ws = (char*)d_ws;
  unsigned short* Pnb = (unsigned short*)ws;               // CPAD*128 bf16 = 25.6 MB
  float* Xn = (float*)(ws + (size_t)CPAD * D_N * 2);       // 512*128
  float* Pb = Xn + B_N * D_N;                              // 512*128
  float* X2 = Pb + B_N * D_N;                              // 512*128
  float* dg = X2 + B_N * D_N;                              // 512
  float* S = dg + B_N;                                     // 512
  float* lossT = S + B_N;                                  // 512
  float* sumexpP = lossT + B_N;                            // 512*16 (line-padded)
  unsigned short* Xsb = (unsigned short*)(sumexpP + B_N * 16);  // 512*128 bf16
  float* A = (float*)(Xsb + B_N * D_N);                    // 512*512
  int* ctrs = (int*)(A + B_N * B_N);                       // [32] = arrive counter

  kA<<<K5_BLOCKS + B_N, 256, 0, stream>>>(X, proxies, T, Xn, Pb, dg, X2, Pnb);
  k3_att<<<B_N, 256, 0, stream>>>(Xn, Pb, dg, A, S);
  k4a_aw<<<dim3(B_N, 4), 128, 0, stream>>>(Xn, A, S, X2);
  k4b_xs<<<B_N, 128, 0, stream>>>(Xn, X2, Pb, Xsb, lossT, sumexpP, ctrs);
  k6_big<<<dim3(K6_GX, K6_GY), 256, 0, stream>>>(Pnb, Xsb, sumexpP, lossT, ctrs, out);
}

// Round 7
// 161.131 us; speedup vs baseline: 1.1890x; 1.1890x over previous
//
#include <hip/hip_runtime.h>
#include <hip/hip_bf16.h>
#include <math.h>

#define B_N 512
#define C_N 100000
#define CPAD 100032          // padded to multiple of 64
#define D_N 128
#define NCHUNK (CPAD / 64)   // 1563
#define K5_BLOCKS (CPAD / 4) // 25008
#define K6_GX 256
#define K6_GY 4
#define K6_BLOCKS (K6_GX * K6_GY)
// each proxy pad row (zero vector) contributes exp(-18) to every row's sumexp
#define PAD_CORR (32.0f * 1.522998e-8f)

typedef short short8 __attribute__((ext_vector_type(8)));
typedef float f32x4 __attribute__((ext_vector_type(4)));

__device__ __forceinline__ unsigned short f2bf(float f) {
  unsigned int u = __float_as_uint(f);
  u += 0x7fffu + ((u >> 16) & 1u);
  return (unsigned short)(u >> 16);
}

__device__ __forceinline__ void gl_lds16(const void* g, void* l) {
  __builtin_amdgcn_global_load_lds(
      (const __attribute__((address_space(1))) void*)g,
      (__attribute__((address_space(3))) void*)l, 16, 0, 0);
}

template <int NT>
__device__ __forceinline__ float block_reduce_sum(float v, float* red) {
  int t = threadIdx.x;
  __syncthreads();
  red[t] = v;
  __syncthreads();
#pragma unroll
  for (int s = NT / 2; s > 0; s >>= 1) {
    if (t < s) red[t] += red[t + s];
    __syncthreads();
  }
  return red[0];
}

// kA: fused proxy-normalize (blocks [0,K5_BLOCKS)) + X-normalize/Pb/diag + X2 zero
__global__ __launch_bounds__(256) void kA(const float* __restrict__ X,
                                          const float* __restrict__ proxies,
                                          const int* __restrict__ T,
                                          float* __restrict__ Xn, float* __restrict__ Pb,
                                          float* __restrict__ diagv, float* __restrict__ X2,
                                          unsigned short* __restrict__ Pnb) {
  int bid = blockIdx.x;
  int t = threadIdx.x;
  if (bid < K5_BLOCKS) {
    int lane = t & 63;
    int row = bid * 4 + (t >> 6);
    float2 v = make_float2(0.f, 0.f);
    if (row < C_N) v = *(const float2*)(proxies + (size_t)row * D_N + 2 * lane);
    float ss = v.x * v.x + v.y * v.y;
#pragma unroll
    for (int off = 1; off < 64; off <<= 1) ss += __shfl_xor(ss, off);
    float inv = 1.f / fmaxf(sqrtf(ss), 1e-12f);
    unsigned short a = f2bf(v.x * inv), b = f2bf(v.y * inv);
    unsigned int pk = (unsigned int)a | ((unsigned int)b << 16);
    *(unsigned int*)(Pnb + (size_t)row * D_N + 2 * lane) = pk;  // pad rows -> exact zeros
  } else {
    __shared__ float red[256];
    int b = bid - K5_BLOCKS;
    bool act = t < D_N;
    float v = act ? X[b * D_N + t] : 0.f;
    float ss = block_reduce_sum<256>(v * v, red);
    float xn = v / fmaxf(sqrtf(ss), 1e-12f);
    if (act) {
      Xn[b * D_N + t] = xn;
      X2[b * D_N + t] = 0.f;
    }
    int row = T[b];
    float p = act ? proxies[(size_t)row * D_N + t] : 0.f;
    float ss2 = block_reduce_sum<256>(p * p, red);
    float pn = p / fmaxf(sqrtf(ss2), 1e-12f);
    if (act) Pb[b * D_N + t] = pn;
    float d = block_reduce_sum<256>(pn * xn, red);
    if (t == 0) diagv[b] = d;
  }
}

// K3: A[b,k] = relu(0.5*(Pb[b].Xn[k]+diag[k])) + relu(Xn[b].Xn[k]); S[b]=row sum
__global__ __launch_bounds__(256) void k3_att(const float* __restrict__ Xn,
                                              const float* __restrict__ Pb,
                                              const float* __restrict__ diagv,
                                              float* __restrict__ A, float* __restrict__ S) {
  __shared__ float xb[128], pbv[128];
  __shared__ float red[256];
  int b = blockIdx.x, t = threadIdx.x;
  if (t < 128) {
    xb[t] = Xn[b * D_N + t];
    pbv[t] = Pb[b * D_N + t];
  }
  __syncthreads();
  float rs = 0.f;
  for (int k = t; k < B_N; k += 256) {
    const float4* xr = (const float4*)(Xn + (size_t)k * D_N);
    float d1 = 0.f, d2 = 0.f;
#pragma unroll
    for (int i = 0; i < 32; i++) {
      float4 v = xr[i];
      d1 += pbv[4 * i] * v.x + pbv[4 * i + 1] * v.y + pbv[4 * i + 2] * v.z + pbv[4 * i + 3] * v.w;
      d2 += xb[4 * i] * v.x + xb[4 * i + 1] * v.y + xb[4 * i + 2] * v.z + xb[4 * i + 3] * v.w;
    }
    float a = fmaxf(0.5f * (d1 + diagv[k]), 0.f) + fmaxf(d2, 0.f);
    A[(size_t)b * B_N + k] = a;
    rs += a;
  }
  rs = block_reduce_sum<256>(rs, red);
  if (t == 0) S[b] = rs;
}

// K4a: X2[b,:] += sum over k-slice of (A[b,k]/(S[k]+eps)) * Xn[k,:]   grid (512,4)
__global__ void k4a_aw(const float* __restrict__ Xn, const float* __restrict__ A,
                       const float* __restrict__ S, float* __restrict__ X2) {
  __shared__ float aw[128];
  int b = blockIdx.x, t = threadIdx.x;
  int k0 = blockIdx.y * 128;
  aw[t] = A[(size_t)b * B_N + k0 + t] / (S[k0 + t] + 1e-5f);
  __syncthreads();
  float acc = 0.f;
#pragma unroll 16
  for (int kk = 0; kk < 128; kk++) acc += aw[kk] * Xn[(size_t)(k0 + kk) * D_N + t];
  atomicAdd(&X2[b * D_N + t], acc);
}

// K4b: Xsb = bf16(3*l2norm(Xn+X2)); lossT[b] = max(18-6*Xs.Pb,0); zero k6 state
__global__ void k4b_xs(const float* __restrict__ Xn, const float* __restrict__ X2,
                       const float* __restrict__ Pb, unsigned short* __restrict__ Xsb,
                       float* __restrict__ lossT, float* __restrict__ sumexpP,
                       int* __restrict__ ctrs) {
  __shared__ float red[128];
  int b = blockIdx.x, t = threadIdx.x;
  float x2 = Xn[b * D_N + t] + X2[b * D_N + t];
  float ss = block_reduce_sum<128>(x2 * x2, red);
  float xs = 3.f * x2 / fmaxf(sqrtf(ss), 1e-12f);
  Xsb[b * D_N + t] = f2bf(xs);
  float dt = block_reduce_sum<128>(xs * Pb[b * D_N + t], red);
  if (t == 0) {
    lossT[b] = fmaxf(18.f - 6.f * dt, 0.f);
    sumexpP[b * 16] = 0.f;
    if (b == 0) ctrs[32] = 0;  // arrive counter, own cache line
  }
}

// K6: Dm[b,c] = max(18 - 6*dot(Xs[b], Pn[c]), 0); sumexp[b] += sum_c exp(-Dm)
// grid (256,4), block 256, tile 128 b x 64 c. Shared-LDS DMA staging (4x dedup)
// with AITER-style pipelining: raw s_barrier + manual s_waitcnt vmcnt(4)
// instead of __syncthreads (which emits vmcnt(0) and drains the in-flight
// next-buffer DMA every iteration -- the m97 structural stall, ~26 us here).
// Each STAGE issues exactly 4 global_load_lds per wave, so vmcnt<=4 completes
// the current buffer while the next buffer's 4 loads stay in flight across
// the barrier. Trailing s_barrier releases the buffer for restage (WAR).
__global__ __launch_bounds__(256, 4) void k6_big(const unsigned short* __restrict__ Pnb,
                                                 const unsigned short* __restrict__ Xsb,
                                                 float* __restrict__ sumexpP,
                                                 const float* __restrict__ lossT,
                                                 int* __restrict__ ctrs,
                                                 float* __restrict__ out) {
  __shared__ __align__(16) unsigned short sP[2][64 * 128];  // 2 x 16 KB, XOR-swizzled
  __shared__ float redf[256];
  __shared__ int sLast;
  const int t = threadIdx.x;
  const int w = t >> 6;
  const int lane = t & 63;
  const int lc = lane & 15;
  const int q = lane >> 4;
  const int b0 = blockIdx.y * 128;

  // A-fragments once from global bf16 Xsb: A[m=lc][k=ks*32+q*8+j]
  short8 afr[2][4];
#pragma unroll
  for (int mt = 0; mt < 2; mt++)
#pragma unroll
    for (int ks = 0; ks < 4; ks++)
      afr[mt][ks] = *(const short8*)(Xsb + (size_t)(b0 + 32 * w + 16 * mt + lc) * D_N +
                                     ks * 32 + q * 8);

  float pe[2][4];
#pragma unroll
  for (int mt = 0; mt < 2; mt++)
#pragma unroll
    for (int r = 0; r < 4; r++) pe[mt][r] = 0.f;

  // staging: wave w stages rows 16w..16w+15 (4 instr x 1024 B); dest granule
  // (R,P) holds global granule g = P ^ (R&15) (bank swizzle, DMA-compatible).
  const int rR = 16 * w + (lane >> 4);
  const int gsrc0 = (lane & 15);
#define STAGE(c0_, buf_)                                                              \
  {                                                                                   \
    _Pragma("unroll") for (int j = 0; j < 4; j++) {                                   \
      int R = rR + 4 * j;                                                             \
      int g = gsrc0 ^ ((R)&15);                                                       \
      gl_lds16(Pnb + (((size_t)(c0_) + R) << 7) + (g << 3),                           \
               &sP[buf_][w * 2048 + j * 512]);                                        \
    }                                                                                 \
  }

  int cc = blockIdx.x;
  STAGE(cc * 64, 0);
  int buf = 0;
  while (true) {
    int nc = cc + gridDim.x;
    if (nc < NCHUNK) STAGE(nc * 64, buf ^ 1);  // issue next-buffer DMA early
    __builtin_amdgcn_sched_barrier(0);         // keep stage issue above the wait
    __builtin_amdgcn_s_waitcnt(0x0F74);        // vmcnt<=4: current buf landed, next in flight
    __builtin_amdgcn_s_barrier();              // rendezvous (NO vmcnt(0) drain)
    __builtin_amdgcn_sched_barrier(0);         // no ds_read hoist above barrier

    f32x4 acc[2][4];
#pragma unroll
    for (int mt = 0; mt < 2; mt++)
#pragma unroll
      for (int nt = 0; nt < 4; nt++) acc[mt][nt] = (f32x4){0.f, 0.f, 0.f, 0.f};

#pragma unroll
    for (int ks = 0; ks < 4; ks++) {
      short8 bfr[4];
#pragma unroll
      for (int nt = 0; nt < 4; nt++) {
        int R = 16 * nt + lc;
        int g = (ks * 4 + q) ^ lc;  // R&15 == lc
        bfr[nt] = *(const short8*)(&sP[buf][R * 128 + (g << 3)]);
      }
#pragma unroll
      for (int nt = 0; nt < 4; nt++)
#pragma unroll
        for (int mt = 0; mt < 2; mt++)
          acc[mt][nt] = __builtin_amdgcn_mfma_f32_16x16x32_bf16(afr[mt][ks], bfr[nt],
                                                                acc[mt][nt], 0, 0, 0);
    }

    // epilogue: no bounds predicate — pad rows are zero vectors, corrected at end
#pragma unroll
    for (int mt = 0; mt < 2; mt++)
#pragma unroll
      for (int nt = 0; nt < 4; nt++) {
        f32x4 a = acc[mt][nt];
#pragma unroll
        for (int r = 0; r < 4; r++)
          pe[mt][r] += __expf(fminf(6.f * a[r] - 18.f, 0.f));
      }

    if (nc >= NCHUNK) break;
    __builtin_amdgcn_sched_barrier(0);  // ds_reads stay above the release barrier
    __builtin_amdgcn_s_barrier();       // all waves done reading buf -> restage safe
    cc = nc;
    buf ^= 1;
  }

  // reduce over 16 col-lanes; one padded atomic per row
#pragma unroll
  for (int mt = 0; mt < 2; mt++) {
#pragma unroll
    for (int r = 0; r < 4; r++) {
      float p = pe[mt][r];
      p += __shfl_xor(p, 1);
      p += __shfl_xor(p, 2);
      p += __shfl_xor(p, 4);
      p += __shfl_xor(p, 8);
      if (lc == 0) {
        int rb = b0 + 32 * w + 16 * mt + 4 * q + r;
        atomicAdd(&sumexpP[rb * 16], p);
      }
    }
  }

  // fused k7: last block to arrive reduces the loss. Atomics complete at the
  // device coherence point; ordering needs only vmcnt(0) (NO threadfence --
  // agent fences emit L2 writeback/invalidate, measured ~46 us over the grid).
  __builtin_amdgcn_s_waitcnt(0);
  if (t == 0) sLast = atomicAdd(&ctrs[32], 1);
  __syncthreads();
  if (sLast == K6_BLOCKS - 1) {
    float v = 0.f;
#pragma unroll
    for (int i = 0; i < 2; i++) {
      int b = t + 256 * i;
      float se = __hip_atomic_load(&sumexpP[b * 16], __ATOMIC_RELAXED,
                                   __HIP_MEMORY_SCOPE_AGENT);
      v += lossT[b] + logf(se - PAD_CORR);
    }
    float s = block_reduce_sum<256>(v, redf);
    if (t == 0) out[0] = s * (1.0f / 512.0f);
  }
}

extern "C" void kernel_launch(void* const* d_in, const int* in_sizes, int n_in,
                              void* d_out, int out_size, void* d_ws, size_t ws_size,
                              hipStream_t stream) {
  const float* X = (const float*)d_in[0];
  const int* T = (const int*)d_in[2];
  const float* proxies = (const float*)d_in[3];
  float* out = (float*)d_out;

  char* ws = (char*)d_ws;
  unsigned short* Pnb = (unsigned short*)ws;               // CPAD*128 bf16 = 25.6 MB
  float* Xn = (float*)(ws + (size_t)CPAD * D_N * 2);       // 512*128
  float* Pb = Xn + B_N * D_N;                              // 512*128
  float* X2 = Pb + B_N * D_N;                              // 512*128
  float* dg = X2 + B_N * D_N;                              // 512
  float* S = dg + B_N;                                     // 512
  float* lossT = S + B_N;                                  // 512
  float* sumexpP = lossT + B_N;                            // 512*16 (line-padded)
  unsigned short* Xsb = (unsigned short*)(sumexpP + B_N * 16);  // 512*128 bf16
  float* A = (float*)(Xsb + B_N * D_N);                    // 512*512
  int* ctrs = (int*)(A + B_N * B_N);                       // [32] = arrive counter

  kA<<<K5_BLOCKS + B_N, 256, 0, stream>>>(X, proxies, T, Xn, Pb, dg, X2, Pnb);
  k3_att<<<B_N, 256, 0, stream>>>(Xn, Pb, dg, A, S);
  k4a_aw<<<dim3(B_N, 4), 128, 0, stream>>>(Xn, A, S, X2);
  k4b_xs<<<B_N, 128, 0, stream>>>(Xn, X2, Pb, Xsb, lossT, sumexpP, ctrs);
  k6_big<<<dim3(K6_GX, K6_GY), 256, 0, stream>>>(Pnb, Xsb, sumexpP, lossT, ctrs, out);
}

// Round 8
// 160.807 us; speedup vs baseline: 1.1914x; 1.0020x over previous
//
#include <hip/hip_runtime.h>
#include <hip/hip_bf16.h>
#include <math.h>

#define B_N 512
#define C_N 100000
#define CPAD 100032          // padded to multiple of 64
#define D_N 128
#define NCHUNK (CPAD / 64)   // 1563
#define K5_BLOCKS (CPAD / 4) // 25008
#define K6_GX 256
#define K6_GY 2
#define K6_BLOCKS (K6_GX * K6_GY)
// each proxy pad row (zero vector) contributes exp(-18) to every row's sumexp
#define PAD_CORR (32.0f * 1.522998e-8f)

typedef short short8 __attribute__((ext_vector_type(8)));
typedef float f32x4 __attribute__((ext_vector_type(4)));

__device__ __forceinline__ unsigned short f2bf(float f) {
  unsigned int u = __float_as_uint(f);
  u += 0x7fffu + ((u >> 16) & 1u);
  return (unsigned short)(u >> 16);
}

__device__ __forceinline__ void gl_lds16(const void* g, void* l) {
  __builtin_amdgcn_global_load_lds(
      (const __attribute__((address_space(1))) void*)g,
      (__attribute__((address_space(3))) void*)l, 16, 0, 0);
}

template <int NT>
__device__ __forceinline__ float block_reduce_sum(float v, float* red) {
  int t = threadIdx.x;
  __syncthreads();
  red[t] = v;
  __syncthreads();
#pragma unroll
  for (int s = NT / 2; s > 0; s >>= 1) {
    if (t < s) red[t] += red[t + s];
    __syncthreads();
  }
  return red[0];
}

// kA: fused proxy-normalize (blocks [0,K5_BLOCKS)) + X-normalize/Pb/diag + X2 zero
__global__ __launch_bounds__(256) void kA(const float* __restrict__ X,
                                          const float* __restrict__ proxies,
                                          const int* __restrict__ T,
                                          float* __restrict__ Xn, float* __restrict__ Pb,
                                          float* __restrict__ diagv, float* __restrict__ X2,
                                          unsigned short* __restrict__ Pnb) {
  int bid = blockIdx.x;
  int t = threadIdx.x;
  if (bid < K5_BLOCKS) {
    int lane = t & 63;
    int row = bid * 4 + (t >> 6);
    float2 v = make_float2(0.f, 0.f);
    if (row < C_N) v = *(const float2*)(proxies + (size_t)row * D_N + 2 * lane);
    float ss = v.x * v.x + v.y * v.y;
#pragma unroll
    for (int off = 1; off < 64; off <<= 1) ss += __shfl_xor(ss, off);
    float inv = 1.f / fmaxf(sqrtf(ss), 1e-12f);
    unsigned short a = f2bf(v.x * inv), b = f2bf(v.y * inv);
    unsigned int pk = (unsigned int)a | ((unsigned int)b << 16);
    *(unsigned int*)(Pnb + (size_t)row * D_N + 2 * lane) = pk;  // pad rows -> exact zeros
  } else {
    __shared__ float red[256];
    int b = bid - K5_BLOCKS;
    bool act = t < D_N;
    float v = act ? X[b * D_N + t] : 0.f;
    float ss = block_reduce_sum<256>(v * v, red);
    float xn = v / fmaxf(sqrtf(ss), 1e-12f);
    if (act) {
      Xn[b * D_N + t] = xn;
      X2[b * D_N + t] = 0.f;
    }
    int row = T[b];
    float p = act ? proxies[(size_t)row * D_N + t] : 0.f;
    float ss2 = block_reduce_sum<256>(p * p, red);
    float pn = p / fmaxf(sqrtf(ss2), 1e-12f);
    if (act) Pb[b * D_N + t] = pn;
    float d = block_reduce_sum<256>(pn * xn, red);
    if (t == 0) diagv[b] = d;
  }
}

// K3: A[b,k] = relu(0.5*(Pb[b].Xn[k]+diag[k])) + relu(Xn[b].Xn[k]); S[b]=row sum
__global__ __launch_bounds__(256) void k3_att(const float* __restrict__ Xn,
                                              const float* __restrict__ Pb,
                                              const float* __restrict__ diagv,
                                              float* __restrict__ A, float* __restrict__ S) {
  __shared__ float xb[128], pbv[128];
  __shared__ float red[256];
  int b = blockIdx.x, t = threadIdx.x;
  if (t < 128) {
    xb[t] = Xn[b * D_N + t];
    pbv[t] = Pb[b * D_N + t];
  }
  __syncthreads();
  float rs = 0.f;
  for (int k = t; k < B_N; k += 256) {
    const float4* xr = (const float4*)(Xn + (size_t)k * D_N);
    float d1 = 0.f, d2 = 0.f;
#pragma unroll
    for (int i = 0; i < 32; i++) {
      float4 v = xr[i];
      d1 += pbv[4 * i] * v.x + pbv[4 * i + 1] * v.y + pbv[4 * i + 2] * v.z + pbv[4 * i + 3] * v.w;
      d2 += xb[4 * i] * v.x + xb[4 * i + 1] * v.y + xb[4 * i + 2] * v.z + xb[4 * i + 3] * v.w;
    }
    float a = fmaxf(0.5f * (d1 + diagv[k]), 0.f) + fmaxf(d2, 0.f);
    A[(size_t)b * B_N + k] = a;
    rs += a;
  }
  rs = block_reduce_sum<256>(rs, red);
  if (t == 0) S[b] = rs;
}

// K4a: X2[b,:] += sum over k-slice of (A[b,k]/(S[k]+eps)) * Xn[k,:]   grid (512,4)
__global__ void k4a_aw(const float* __restrict__ Xn, const float* __restrict__ A,
                       const float* __restrict__ S, float* __restrict__ X2) {
  __shared__ float aw[128];
  int b = blockIdx.x, t = threadIdx.x;
  int k0 = blockIdx.y * 128;
  aw[t] = A[(size_t)b * B_N + k0 + t] / (S[k0 + t] + 1e-5f);
  __syncthreads();
  float acc = 0.f;
#pragma unroll 16
  for (int kk = 0; kk < 128; kk++) acc += aw[kk] * Xn[(size_t)(k0 + kk) * D_N + t];
  atomicAdd(&X2[b * D_N + t], acc);
}

// K4b: Xsb = bf16(3*l2norm(Xn+X2)); lossT[b] = max(18-6*Xs.Pb,0); zero k6 state
__global__ void k4b_xs(const float* __restrict__ Xn, const float* __restrict__ X2,
                       const float* __restrict__ Pb, unsigned short* __restrict__ Xsb,
                       float* __restrict__ lossT, float* __restrict__ sumexpP,
                       int* __restrict__ ctrs) {
  __shared__ float red[128];
  int b = blockIdx.x, t = threadIdx.x;
  float x2 = Xn[b * D_N + t] + X2[b * D_N + t];
  float ss = block_reduce_sum<128>(x2 * x2, red);
  float xs = 3.f * x2 / fmaxf(sqrtf(ss), 1e-12f);
  Xsb[b * D_N + t] = f2bf(xs);
  float dt = block_reduce_sum<128>(xs * Pb[b * D_N + t], red);
  if (t == 0) {
    lossT[b] = fmaxf(18.f - 6.f * dt, 0.f);
    sumexpP[b * 16] = 0.f;
    if (b == 0) ctrs[32] = 0;  // arrive counter, own cache line
  }
}

// K6: Dm[b,c] = max(18 - 6*dot(Xs[b], Pn[c]), 0); sumexp[b] += sum_c exp(-Dm)
// grid (256,2), block 256, tile 256 b x 64 c (4 m-tiles/wave). R7 post-mortem:
// the loop is per-visit-overhead + LDS-read bound (16 ds_read_b128/wave served
// only 2 m-tiles); doubling m-tiles doubles MFMA per staged byte, halves
// chunk-visits (6252->3126) and Pnb L2 traffic (102->51 MB). ~185 VGPR ->
// 2 waves/SIMD (launch_bounds(256,2)), 2 blocks/CU.
__global__ __launch_bounds__(256, 2) void k6_big(const unsigned short* __restrict__ Pnb,
                                                 const unsigned short* __restrict__ Xsb,
                                                 float* __restrict__ sumexpP,
                                                 const float* __restrict__ lossT,
                                                 int* __restrict__ ctrs,
                                                 float* __restrict__ out) {
  __shared__ __align__(16) unsigned short sP[2][64 * 128];  // 2 x 16 KB, XOR-swizzled
  __shared__ float redf[256];
  __shared__ int sLast;
  const int t = threadIdx.x;
  const int w = t >> 6;
  const int lane = t & 63;
  const int lc = lane & 15;
  const int q = lane >> 4;
  const int b0 = blockIdx.y * 256;

  // A-fragments once from global bf16 Xsb: wave w owns m-rows 64w..64w+63
  short8 afr[4][4];
#pragma unroll
  for (int mt = 0; mt < 4; mt++)
#pragma unroll
    for (int ks = 0; ks < 4; ks++)
      afr[mt][ks] = *(const short8*)(Xsb + (size_t)(b0 + 64 * w + 16 * mt + lc) * D_N +
                                     ks * 32 + q * 8);

  float pe[4][4];
#pragma unroll
  for (int mt = 0; mt < 4; mt++)
#pragma unroll
    for (int r = 0; r < 4; r++) pe[mt][r] = 0.f;

  // staging: wave w stages rows 16w..16w+15 (4 instr x 1024 B); dest granule
  // (R,P) holds global granule g = P ^ (R&15) (bank swizzle, DMA-compatible).
  const int rR = 16 * w + (lane >> 4);
  const int gsrc0 = (lane & 15);
#define STAGE(c0_, buf_)                                                              \
  {                                                                                   \
    _Pragma("unroll") for (int j = 0; j < 4; j++) {                                   \
      int R = rR + 4 * j;                                                             \
      int g = gsrc0 ^ ((R)&15);                                                       \
      gl_lds16(Pnb + (((size_t)(c0_) + R) << 7) + (g << 3),                           \
               &sP[buf_][w * 2048 + j * 512]);                                        \
    }                                                                                 \
  }

  int cc = blockIdx.x;
  STAGE(cc * 64, 0);
  int buf = 0;
  while (true) {
    int nc = cc + gridDim.x;
    if (nc < NCHUNK) STAGE(nc * 64, buf ^ 1);  // issue next-buffer DMA early
    __builtin_amdgcn_sched_barrier(0);         // keep stage issue above the wait
    __builtin_amdgcn_s_waitcnt(0x0F74);        // vmcnt<=4: current buf landed, next in flight
    __builtin_amdgcn_s_barrier();              // rendezvous (NO vmcnt(0) drain)
    __builtin_amdgcn_sched_barrier(0);         // no ds_read hoist above barrier

    f32x4 acc[4][4];
#pragma unroll
    for (int mt = 0; mt < 4; mt++)
#pragma unroll
      for (int nt = 0; nt < 4; nt++) acc[mt][nt] = (f32x4){0.f, 0.f, 0.f, 0.f};

#pragma unroll
    for (int ks = 0; ks < 4; ks++) {
      short8 bfr[4];
#pragma unroll
      for (int nt = 0; nt < 4; nt++) {
        int R = 16 * nt + lc;
        int g = (ks * 4 + q) ^ lc;  // R&15 == lc
        bfr[nt] = *(const short8*)(&sP[buf][R * 128 + (g << 3)]);
      }
#pragma unroll
      for (int nt = 0; nt < 4; nt++)
#pragma unroll
        for (int mt = 0; mt < 4; mt++)
          acc[mt][nt] = __builtin_amdgcn_mfma_f32_16x16x32_bf16(afr[mt][ks], bfr[nt],
                                                                acc[mt][nt], 0, 0, 0);
    }

    // epilogue: no bounds predicate — pad rows are zero vectors, corrected at end
#pragma unroll
    for (int mt = 0; mt < 4; mt++)
#pragma unroll
      for (int nt = 0; nt < 4; nt++) {
        f32x4 a = acc[mt][nt];
#pragma unroll
        for (int r = 0; r < 4; r++)
          pe[mt][r] += __expf(fminf(__fmaf_rn(6.f, a[r], -18.f), 0.f));
      }

    if (nc >= NCHUNK) break;
    __builtin_amdgcn_sched_barrier(0);  // ds_reads stay above the release barrier
    __builtin_amdgcn_s_barrier();       // all waves done reading buf -> restage safe
    cc = nc;
    buf ^= 1;
  }

  // reduce over 16 col-lanes; one padded atomic per row
#pragma unroll
  for (int mt = 0; mt < 4; mt++) {
#pragma unroll
    for (int r = 0; r < 4; r++) {
      float p = pe[mt][r];
      p += __shfl_xor(p, 1);
      p += __shfl_xor(p, 2);
      p += __shfl_xor(p, 4);
      p += __shfl_xor(p, 8);
      if (lc == 0) {
        int rb = b0 + 64 * w + 16 * mt + 4 * q + r;
        atomicAdd(&sumexpP[rb * 16], p);
      }
    }
  }

  // fused k7: last block to arrive reduces the loss. Atomics complete at the
  // device coherence point; ordering needs only vmcnt(0) (NO threadfence --
  // agent fences emit L2 writeback/invalidate, measured ~46 us over the grid).
  __builtin_amdgcn_s_waitcnt(0);
  if (t == 0) sLast = atomicAdd(&ctrs[32], 1);
  __syncthreads();
  if (sLast == K6_BLOCKS - 1) {
    float v = 0.f;
#pragma unroll
    for (int i = 0; i < 2; i++) {
      int b = t + 256 * i;
      float se = __hip_atomic_load(&sumexpP[b * 16], __ATOMIC_RELAXED,
                                   __HIP_MEMORY_SCOPE_AGENT);
      v += lossT[b] + logf(se - PAD_CORR);
    }
    float s = block_reduce_sum<256>(v, redf);
    if (t == 0) out[0] = s * (1.0f / 512.0f);
  }
}

extern "C" void kernel_launch(void* const* d_in, const int* in_sizes, int n_in,
                              void* d_out, int out_size, void* d_ws, size_t ws_size,
                              hipStream_t stream) {
  const float* X = (const float*)d_in[0];
  const int* T = (const int*)d_in[2];
  const float* proxies = (const float*)d_in[3];
  float* out = (float*)d_out;

  char* ws = (char*)d_ws;
  unsigned short* Pnb = (unsigned short*)ws;               // CPAD*128 bf16 = 25.6 MB
  float* Xn = (float*)(ws + (size_t)CPAD * D_N * 2);       // 512*128
  float* Pb = Xn + B_N * D_N;                              // 512*128
  float* X2 = Pb + B_N * D_N;                              // 512*128
  float* dg = X2 + B_N * D_N;                              // 512
  float* S = dg + B_N;                                     // 512
  float* lossT = S + B_N;                                  // 512
  float* sumexpP = lossT + B_N;                            // 512*16 (line-padded)
  unsigned short* Xsb = (unsigned short*)(sumexpP + B_N * 16);  // 512*128 bf16
  float* A = (float*)(Xsb + B_N * D_N);                    // 512*512
  int* ctrs = (int*)(A + B_N * B_N);                       // [32] = arrive counter

  kA<<<K5_BLOCKS + B_N, 256, 0, stream>>>(X, proxies, T, Xn, Pb, dg, X2, Pnb);
  k3_att<<<B_N, 256, 0, stream>>>(Xn, Pb, dg, A, S);
  k4a_aw<<<dim3(B_N, 4), 128, 0, stream>>>(Xn, A, S, X2);
  k4b_xs<<<B_N, 128, 0, stream>>>(Xn, X2, Pb, Xsb, lossT, sumexpP, ctrs);
  k6_big<<<dim3(K6_GX, K6_GY), 256, 0, stream>>>(Pnb, Xsb, sumexpP, lossT, ctrs, out);
}